// Round 11
// baseline (318.949 us; speedup 1.0000x reference)
//
#include <hip/hip_runtime.h>
#include <hip/hip_bf16.h>
#include <math.h>
#include <stdint.h>

typedef __bf16 bf16_t;
typedef __bf16 bf16x4 __attribute__((ext_vector_type(4)));
typedef __bf16 bf16x8 __attribute__((ext_vector_type(8)));
typedef float floatx4 __attribute__((ext_vector_type(4)));

#define BM 128
#define BK 32

// fragment-tiled address: 16-row x 32-k tiles, chunk-major inside
//   addr(m,k,KT) = ((m>>4)*KT + (k>>5))*512 + (((k>>3)&3)*16 + (m&15))*8 + (k&7)
__device__ __forceinline__ size_t ftaddr(int m, int k, int KT) {
    return ((size_t)(m >> 4) * KT + (k >> 5)) * 512
         + (((k >> 3) & 3) * 16 + (m & 15)) * 8 + (k & 7);
}

__device__ __forceinline__ void gload16(const void* g, void* lds) {
    __builtin_amdgcn_global_load_lds(
        (__attribute__((address_space(1))) void*)(uintptr_t)g,
        (__attribute__((address_space(3))) void*)(uintptr_t)lds,
        16, 0, 0);
}

// ---------------- merged transpose + cast fp32 -> bf16, FRAGMENT-TILED ---
__global__ void transpose_all(const float* __restrict__ wq, const float* __restrict__ wk,
                              const float* __restrict__ wv, const float* __restrict__ w_proj,
                              const float* __restrict__ w1, const float* __restrict__ w2,
                              bf16_t* __restrict__ WQKVT, bf16_t* __restrict__ WPROJT,
                              bf16_t* __restrict__ W1T, bf16_t* __restrict__ W2T)
{
    const int idx = blockIdx.x;
    const float* in; bf16_t* out; int R, C, rt, ct; long nrow0;
    if (idx < 768) {                       // wq/wk/wv: [16][1024][64] per head
        const int z = idx >> 8;
        const int hd = (idx >> 4) & 15;
        rt = idx & 15; ct = 0; R = 1024; C = 64;
        in  = (z == 0 ? wq : z == 1 ? wk : wv) + hd * 65536;
        out = WQKVT; nrow0 = z * 1024 + hd * 64;
    } else if (idx < 1024) {               // w_proj: [1024][1024]
        const int t = idx - 768; rt = t & 15; ct = t >> 4; R = 1024; C = 1024;
        in = w_proj; out = WPROJT; nrow0 = 0;
    } else if (idx < 2048) {               // w1: [1024][4096]
        const int t = idx - 1024; rt = t & 15; ct = t >> 4; R = 1024; C = 4096;
        in = w1; out = W1T; nrow0 = 0;
    } else {                               // w2: [4096][1024]
        const int t = idx - 2048; rt = t & 63; ct = t >> 6; R = 4096; C = 1024;
        in = w2; out = W2T; nrow0 = 0;
    }
    __shared__ float tile[64][65];
    const int tid = threadIdx.x;
    const int r0 = rt * 64, c0 = ct * 64;
    const int tr = tid >> 4;
    const int tc = (tid & 15) * 4;
#pragma unroll
    for (int rr = 0; rr < 4; rr++) {
        const int r = tr + rr * 16;
        const float4 v = *(const float4*)&in[(long)(r0 + r) * C + c0 + tc];
        tile[r][tc + 0] = v.x; tile[r][tc + 1] = v.y;
        tile[r][tc + 2] = v.z; tile[r][tc + 3] = v.w;
    }
    __syncthreads();
    const int KT = R >> 5;
#pragma unroll
    for (int rr = 0; rr < 4; rr++) {
        const int c = tr + rr * 16;
        const long n = nrow0 + c0 + c;     // output row (N dim)
        const int k = r0 + tc;             // k (4 consecutive, k&7 in {0,4})
        bf16x4 o;
        o[0] = (bf16_t)tile[tc + 0][c];
        o[1] = (bf16_t)tile[tc + 1][c];
        o[2] = (bf16_t)tile[tc + 2][c];
        o[3] = (bf16_t)tile[tc + 3][c];
        *(bf16x4*)&out[ftaddr((int)n, k, KT)] = o;
    }
}

// ---------------- layernorm (fp32 in, bf16 FRAGMENT-TILED out) -----------
__global__ void ln_kernel(const float* __restrict__ x, const float* __restrict__ g,
                          const float* __restrict__ b, bf16_t* __restrict__ outb)
{
    const int row = blockIdx.x;
    const int tid = threadIdx.x;
    const float4 v = ((const float4*)(x + (long)row * 1024))[tid];
    float s  = v.x + v.y + v.z + v.w;
    float s2 = v.x * v.x + v.y * v.y + v.z * v.z + v.w * v.w;
#pragma unroll
    for (int off = 32; off >= 1; off >>= 1) {
        s  += __shfl_xor(s, off);
        s2 += __shfl_xor(s2, off);
    }
    __shared__ float red[8];
    const int wv = tid >> 6;
    if ((tid & 63) == 0) { red[wv] = s; red[4 + wv] = s2; }
    __syncthreads();
    s  = red[0] + red[1] + red[2] + red[3];
    s2 = red[4] + red[5] + red[6] + red[7];
    const float mu  = s * (1.0f / 1024.0f);
    const float var = fmaxf(s2 * (1.0f / 1024.0f) - mu * mu, 0.0f);
    const float rs  = rsqrtf(var + 1e-5f);
    const float4 gv = ((const float4*)g)[tid];
    const float4 bv = ((const float4*)b)[tid];
    bf16x4 o;
    o[0] = (bf16_t)((v.x - mu) * rs * gv.x + bv.x);
    o[1] = (bf16_t)((v.y - mu) * rs * gv.y + bv.y);
    o[2] = (bf16_t)((v.z - mu) * rs * gv.z + bv.z);
    o[3] = (bf16_t)((v.w - mu) * rs * gv.w + bv.w);
    *(bf16x4*)&outb[ftaddr(row, tid * 4, 32)] = o;
}

// ---------------- double layernorm fused: ln(ln(x)) -> bf16 tiled --------
__global__ void ln2x_kernel(const float* __restrict__ x, const float* __restrict__ g,
                            const float* __restrict__ b, bf16_t* __restrict__ outb)
{
    const int row = blockIdx.x;
    const int tid = threadIdx.x;
    const float4 v = ((const float4*)(x + (long)row * 1024))[tid];
    float s  = v.x + v.y + v.z + v.w;
    float s2 = v.x * v.x + v.y * v.y + v.z * v.z + v.w * v.w;
#pragma unroll
    for (int off = 32; off >= 1; off >>= 1) {
        s  += __shfl_xor(s, off);
        s2 += __shfl_xor(s2, off);
    }
    __shared__ float red[8];
    __shared__ float red2[8];
    const int wv = tid >> 6;
    if ((tid & 63) == 0) { red[wv] = s; red[4 + wv] = s2; }
    __syncthreads();
    s  = red[0] + red[1] + red[2] + red[3];
    s2 = red[4] + red[5] + red[6] + red[7];
    float mu  = s * (1.0f / 1024.0f);
    float var = fmaxf(s2 * (1.0f / 1024.0f) - mu * mu, 0.0f);
    float rs  = rsqrtf(var + 1e-5f);
    const float4 gv = ((const float4*)g)[tid];
    const float4 bv = ((const float4*)b)[tid];
    float y0 = (v.x - mu) * rs * gv.x + bv.x;
    float y1 = (v.y - mu) * rs * gv.y + bv.y;
    float y2 = (v.z - mu) * rs * gv.z + bv.z;
    float y3 = (v.w - mu) * rs * gv.w + bv.w;
    s  = y0 + y1 + y2 + y3;
    s2 = y0 * y0 + y1 * y1 + y2 * y2 + y3 * y3;
#pragma unroll
    for (int off = 32; off >= 1; off >>= 1) {
        s  += __shfl_xor(s, off);
        s2 += __shfl_xor(s2, off);
    }
    if ((tid & 63) == 0) { red2[wv] = s; red2[4 + wv] = s2; }
    __syncthreads();
    s  = red2[0] + red2[1] + red2[2] + red2[3];
    s2 = red2[4] + red2[5] + red2[6] + red2[7];
    mu  = s * (1.0f / 1024.0f);
    var = fmaxf(s2 * (1.0f / 1024.0f) - mu * mu, 0.0f);
    rs  = rsqrtf(var + 1e-5f);
    bf16x4 o;
    o[0] = (bf16_t)((y0 - mu) * rs * gv.x + bv.x);
    o[1] = (bf16_t)((y1 - mu) * rs * gv.y + bv.y);
    o[2] = (bf16_t)((y2 - mu) * rs * gv.z + bv.z);
    o[3] = (bf16_t)((y3 - mu) * rs * gv.w + bv.w);
    *(bf16x4*)&outb[ftaddr(row, tid * 4, 32)] = o;
}

// ---------------- bf16 MFMA GEMM: C = Atiled * Btiled^T ------------------
// BOTH operands fragment-tiled in global memory: every gload16 is a
// contiguous 1024B burst landing in LDS in MFMA fragment order; ALL fragment
// reads are base + lane*16B — zero bank conflicts (R10: B-tiling cut
// conflicts 6.3M->2.1M and FF2 61->56us; this removes A's remaining 2.1M).
// Triple-buffered, fine vmcnt + raw s_barrier (R6 pipeline).
// EPI: 0=QKV scatter, 1=proj(+bias+resid->f32), 2=relu(+bias)->bf16 tiled,
//      3=final(+bias+resid)->f32
template<int EPI, int BNt>
__global__ __launch_bounds__(256, 2)
void gemm_bt(const bf16_t* __restrict__ A, const bf16_t* __restrict__ Bt,
             const int K,
             const float* __restrict__ bias, const float* __restrict__ resid,
             float* __restrict__ outf, bf16_t* __restrict__ outb,
             bf16_t* __restrict__ aux1, bf16_t* __restrict__ aux2,
             const int Nout)
{
    constexpr int NFRAG = BNt / 16;
    __shared__ __align__(16) bf16_t As[3][8 * 512];
    __shared__ __align__(16) bf16_t Bs[3][NFRAG * 512];
    const int tid  = threadIdx.x;
    const int wave = tid >> 6, lane = tid & 63;
    const int bm = blockIdx.x * BM, bn = blockIdx.y * BNt;
    const int KT = K >> 5;

    floatx4 acc[2][NFRAG];
#pragma unroll
    for (int i = 0; i < 2; i++)
#pragma unroll
        for (int j = 0; j < NFRAG; j++) acc[i][j] = (floatx4){0.f, 0.f, 0.f, 0.f};

    // A staging: fragment-tiled rowblocks bm/16 + wave*2 + {0,1}
    const bf16_t* gA0 = A + ((size_t)(bm / 16 + wave * 2 + 0) * KT) * 512 + lane * 8;
    const bf16_t* gA1 = A + ((size_t)(bm / 16 + wave * 2 + 1) * KT) * 512 + lane * 8;
    const int lA0 = (wave * 2 + 0) * 512;
    const int lA1 = (wave * 2 + 1) * 512;

    // B staging: fragment-tiled
    const bf16_t* gB0;
    const bf16_t* gB1 = nullptr;
    int lB0, lB1 = 0;
    if (BNt == 128) {
        gB0 = Bt + ((size_t)(bn / 16 + wave * 2 + 0) * KT) * 512 + lane * 8;
        gB1 = Bt + ((size_t)(bn / 16 + wave * 2 + 1) * KT) * 512 + lane * 8;
        lB0 = (wave * 2 + 0) * 512;
        lB1 = (wave * 2 + 1) * 512;
    } else {
        gB0 = Bt + ((size_t)(bn / 16 + wave) * KT) * 512 + lane * 8;
        lB0 = wave * 512;
    }

    auto stage = [&](int t, int bu) {
        const size_t off = (size_t)t * 512;
        gload16(gA0 + off, (bf16_t*)As[bu] + lA0);
        gload16(gA1 + off, (bf16_t*)As[bu] + lA1);
        gload16(gB0 + off, (bf16_t*)Bs[bu] + lB0);
        if (BNt == 128) gload16(gB1 + off, (bf16_t*)Bs[bu] + lB1);
    };

    auto compute = [&](int bu) {
        bf16x8 af[2], bfv[NFRAG];
#pragma unroll
        for (int i = 0; i < 2; i++)
            af[i] = *(const bf16x8*)&As[bu][(wave * 2 + i) * 512 + lane * 8];
#pragma unroll
        for (int j = 0; j < NFRAG; j++)
            bfv[j] = *(const bf16x8*)&Bs[bu][j * 512 + lane * 8];
#pragma unroll
        for (int i = 0; i < 2; i++)
#pragma unroll
            for (int j = 0; j < NFRAG; j++)
                acc[i][j] = __builtin_amdgcn_mfma_f32_16x16x32_bf16(af[i], bfv[j], acc[i][j], 0, 0, 0);
    };

    const int NT = K / BK;
    stage(0, 0);
    stage(1, 1);
    int bu = 0;
    for (int t = 0; t < NT - 1; ++t) {
        if (BNt == 128) asm volatile("s_waitcnt vmcnt(4)\n\ts_barrier" ::: "memory");
        else            asm volatile("s_waitcnt vmcnt(3)\n\ts_barrier" ::: "memory");
        if (t + 2 < NT) stage(t + 2, (t + 2) % 3);
        compute(bu);
        bu = (bu + 1) % 3;
    }
    asm volatile("s_waitcnt vmcnt(0)\n\ts_barrier" ::: "memory");
    compute(bu);

    // epilogue: C/D layout row=(lane>>4)*4+r, col=lane&15
    const int er = (lane >> 4) * 4, ec = lane & 15;
#pragma unroll
    for (int i = 0; i < 2; i++) {
#pragma unroll
        for (int j = 0; j < NFRAG; j++) {
            const int col = bn + j * 16 + ec;
#pragma unroll
            for (int r = 0; r < 4; r++) {
                const int row = bm + wave * 32 + i * 16 + er + r;
                const float v = acc[i][j][r];
                if (EPI == 0) {
                    const int b = row >> 10, t = row & 1023;
                    if (col < 1024) {
                        const int h = col >> 6, d = col & 63;
                        outb[(size_t)((b * 16 + h) * 1024 + t) * 64 + d] = (bf16_t)v;
                    } else if (col < 2048) {
                        const int c2 = col - 1024, h = c2 >> 6, d = c2 & 63;
                        aux1[(size_t)((b * 16 + h) * 1024 + t) * 64 + d] = (bf16_t)v;
                    } else {
                        const int c2 = col - 2048, h = c2 >> 6, d = c2 & 63;
                        aux2[(size_t)((b * 16 + h) * 64 + d) * 1024 + t] = (bf16_t)v;
                    }
                } else if (EPI == 1 || EPI == 3) {
                    const size_t idx = (size_t)row * Nout + col;
                    outf[idx] = v + bias[col] + resid[idx];
                } else if (EPI == 2) {
                    // fragment-tiled store (consumed as A by FF2)
                    outb[ftaddr(row, col, Nout >> 5)] = (bf16_t)fmaxf(v + bias[col], 0.f);
                }
            }
        }
    }
}

// ---------------- flash attention: Q[BH,T,64], K[BH,T,64], Vt[BH,64,T] ----
// Output AO written FRAGMENT-TILED (consumed as A by proj GEMM).
__global__ __launch_bounds__(256, 4)
void attn_kernel(const bf16_t* __restrict__ Q, const bf16_t* __restrict__ Kg,
                 const bf16_t* __restrict__ Vt, bf16_t* __restrict__ Og)
{
    __shared__ __align__(16) bf16_t Ks[2][4096];
    __shared__ __align__(16) bf16_t Vs[2][4096];
    __shared__ __align__(16) bf16_t Ps[4][1024];
    const int tid = threadIdx.x, wave = tid >> 6, lane = tid & 63;
    const int bh = blockIdx.y;
    const int b = bh >> 4, h = bh & 15;
    const int q0 = blockIdx.x * 64 + wave * 16;
    const bf16_t* Qb = Q + (size_t)bh * 65536;
    const char* Kb = (const char*)(Kg + (size_t)bh * 65536);
    const char* Vb = (const char*)(Vt + (size_t)bh * 65536);
    const int fr = lane & 15, g = lane >> 4, fk = g * 8;

    const bf16x8 qf0 = *(const bf16x8*)&Qb[(size_t)(q0 + fr) * 64 + fk];
    const bf16x8 qf1 = *(const bf16x8*)&Qb[(size_t)(q0 + fr) * 64 + 32 + fk];

    floatx4 o[4];
#pragma unroll
    for (int dt = 0; dt < 4; dt++) o[dt] = (floatx4){0.f, 0.f, 0.f, 0.f};
    float lsum[4] = {0.f, 0.f, 0.f, 0.f};
    bf16_t* pw = &Ps[wave][0];
    const float sscale = 0.125f * 1.44269504088896f;

    auto stage = [&](int s0, int bu) {
#pragma unroll
        for (int t = 0; t < 2; t++) {
            const int j = wave * 2 + t;
            gload16(Kb + (size_t)(s0 + lane) * 128 + j * 16, &Ks[bu][j * 512]);
            gload16(Vb + (size_t)lane * 2048 + (size_t)s0 * 2 + j * 16, &Vs[bu][j * 512]);
        }
    };

    stage(0, 0);
    int bu = 0;
    for (int it = 0; it < 16; ++it) {
        __syncthreads();
        if (it < 15) stage((it + 1) * 64, bu ^ 1);
        const bf16_t* Kl = Ks[bu];
        const bf16_t* Vl = Vs[bu];

        floatx4 sacc[4];
#pragma unroll
        for (int ss = 0; ss < 4; ss++) sacc[ss] = (floatx4){0.f, 0.f, 0.f, 0.f};
#pragma unroll
        for (int c = 0; c < 2; c++) {
            const int ch = c * 4 + g;
            const bf16x8 qf = (c == 0) ? qf0 : qf1;
#pragma unroll
            for (int ss = 0; ss < 4; ss++) {
                const bf16x8 kf = *(const bf16x8*)&Kl[ch * 512 + (ss * 16 + fr) * 8];
                sacc[ss] = __builtin_amdgcn_mfma_f32_16x16x32_bf16(qf, kf, sacc[ss], 0, 0, 0);
            }
        }
#pragma unroll
        for (int ss = 0; ss < 4; ss++) {
#pragma unroll
            for (int r = 0; r < 4; r++) {
                const float p = __builtin_amdgcn_exp2f(sacc[ss][r] * sscale);
                lsum[r] += p;
                const int q = g * 4 + r;
                pw[(ss * 2 + (fr >> 3)) * 128 + q * 8 + (fr & 7)] = (bf16_t)p;
            }
        }
        asm volatile("s_waitcnt lgkmcnt(0)" ::: "memory");
#pragma unroll
        for (int c = 0; c < 2; c++) {
            const int ch = c * 4 + g;
            const bf16x8 pf = *(const bf16x8*)&pw[ch * 128 + fr * 8];
#pragma unroll
            for (int dt = 0; dt < 4; dt++) {
                const bf16x8 vf = *(const bf16x8*)&Vl[ch * 512 + (dt * 16 + fr) * 8];
                o[dt] = __builtin_amdgcn_mfma_f32_16x16x32_bf16(pf, vf, o[dt], 0, 0, 0);
            }
        }
        asm volatile("" ::: "memory");
        bu ^= 1;
    }
#pragma unroll
    for (int r = 0; r < 4; r++) {
        float l = lsum[r];
        l += __shfl_xor(l, 1);
        l += __shfl_xor(l, 2);
        l += __shfl_xor(l, 4);
        l += __shfl_xor(l, 8);
        lsum[r] = 1.0f / l;
    }
    const int tq = q0 + g * 4;
#pragma unroll
    for (int dt = 0; dt < 4; dt++) {
#pragma unroll
        for (int r = 0; r < 4; r++) {
            const int m = b * 1024 + tq + r;
            const int k = h * 64 + dt * 16 + fr;
            Og[ftaddr(m, k, 32)] = (bf16_t)(o[dt][r] * lsum[r]);
        }
    }
}

// -------------------------------------------------------------------------
extern "C" void kernel_launch(void* const* d_in, const int* in_sizes, int n_in,
                              void* d_out, int out_size, void* d_ws, size_t ws_size,
                              hipStream_t stream)
{
    const float* x      = (const float*)d_in[0];
    const float* wq     = (const float*)d_in[1];
    const float* wk     = (const float*)d_in[2];
    const float* wv     = (const float*)d_in[3];
    const float* w_proj = (const float*)d_in[4];
    const float* b_proj = (const float*)d_in[5];
    const float* w1     = (const float*)d_in[6];
    const float* b1     = (const float*)d_in[7];
    const float* w2     = (const float*)d_in[8];
    const float* b2     = (const float*)d_in[9];
    const float* g1     = (const float*)d_in[10];
    const float* be1    = (const float*)d_in[11];
    const float* g2     = (const float*)d_in[12];
    const float* be2    = (const float*)d_in[13];
    float* out = (float*)d_out;
    char* ws = (char*)d_ws;

    bf16_t* WQKVT = (bf16_t*)(ws + 0x0000000);  // [3072,1024] tiled, 6 MB
    bf16_t* WPROJT= (bf16_t*)(ws + 0x0600000);  // [1024,1024] tiled, 2 MB
    bf16_t* W1T   = (bf16_t*)(ws + 0x0800000);  // [4096,1024] tiled, 8 MB
    bf16_t* W2T   = (bf16_t*)(ws + 0x1000000);  // [1024,4096] tiled, 8 MB
    bf16_t* HB    = (bf16_t*)(ws + 0x1800000);  // ln1 out tiled, 8 MB
    bf16_t* Qb    = (bf16_t*)(ws + 0x2000000);  // [BH,T,64] bf16, 8 MB
    bf16_t* Kb    = (bf16_t*)(ws + 0x2800000);  // [BH,T,64] bf16, 8 MB
    bf16_t* Vtb   = (bf16_t*)(ws + 0x3000000);  // [BH,64,T] bf16, 8 MB
    bf16_t* AO    = (bf16_t*)(ws + 0x3800000);  // attn out tiled, 8 MB
    float*  X2    = (float*)(ws + 0x4000000);   // x+sa fp32 row-major, 16 MB
    bf16_t* TB    = (bf16_t*)(ws + 0x2800000);  // ln2(ln2) tiled (reuses Kb), 8 MB
    bf16_t* FF1B  = (bf16_t*)(ws + 0x5000000);  // [4096,4096] tiled, 32 MB

    dim3 blk(256);
    transpose_all<<<3072, blk, 0, stream>>>(wq, wk, wv, w_proj, w1, w2,
                                            WQKVT, WPROJT, W1T, W2T);
    ln_kernel<<<4096, blk, 0, stream>>>(x, g1, be1, HB);
    gemm_bt<0, 128><<<dim3(32, 24), blk, 0, stream>>>(HB, WQKVT, 1024, nullptr, nullptr,
                                                      nullptr, Qb, Kb, Vtb, 3072);
    attn_kernel<<<dim3(16, 64), blk, 0, stream>>>(Qb, Kb, Vtb, AO);
    gemm_bt<1, 64><<<dim3(32, 16), blk, 0, stream>>>(AO, WPROJT, 1024, b_proj, x,
                                                     X2, nullptr, nullptr, nullptr, 1024);
    ln2x_kernel<<<4096, blk, 0, stream>>>(X2, g2, be2, TB);
    gemm_bt<2, 128><<<dim3(32, 32), blk, 0, stream>>>(TB, W1T, 1024, b1, nullptr,
                                                      nullptr, FF1B, nullptr, nullptr, 4096);
    gemm_bt<3, 64><<<dim3(32, 16), blk, 0, stream>>>(FF1B, W2T, 4096, b2, X2,
                                                     out, nullptr, nullptr, nullptr, 1024);
}

// Round 12
// 316.849 us; speedup vs baseline: 1.0066x; 1.0066x over previous
//
#include <hip/hip_runtime.h>
#include <hip/hip_bf16.h>
#include <math.h>
#include <stdint.h>

typedef __bf16 bf16_t;
typedef __bf16 bf16x4 __attribute__((ext_vector_type(4)));
typedef __bf16 bf16x8 __attribute__((ext_vector_type(8)));
typedef float floatx4 __attribute__((ext_vector_type(4)));

#define BM 128
#define BK 32

// fragment-tiled address: 16-row x 32-k tiles, chunk-major inside
//   addr(m,k,KT) = ((m>>4)*KT + (k>>5))*512 + (((k>>3)&3)*16 + (m&15))*8 + (k&7)
__device__ __forceinline__ size_t ftaddr(int m, int k, int KT) {
    return ((size_t)(m >> 4) * KT + (k >> 5)) * 512
         + (((k >> 3) & 3) * 16 + (m & 15)) * 8 + (k & 7);
}

__device__ __forceinline__ void gload16(const void* g, void* lds) {
    __builtin_amdgcn_global_load_lds(
        (__attribute__((address_space(1))) void*)(uintptr_t)g,
        (__attribute__((address_space(3))) void*)(uintptr_t)lds,
        16, 0, 0);
}

// ---------------- merged transpose + cast fp32 -> bf16, FRAGMENT-TILED ---
// Write phase: one 1024B fragment-tile per wave per iter, lane*16B contiguous.
__global__ void transpose_all(const float* __restrict__ wq, const float* __restrict__ wk,
                              const float* __restrict__ wv, const float* __restrict__ w_proj,
                              const float* __restrict__ w1, const float* __restrict__ w2,
                              bf16_t* __restrict__ WQKVT, bf16_t* __restrict__ WPROJT,
                              bf16_t* __restrict__ W1T, bf16_t* __restrict__ W2T)
{
    const int idx = blockIdx.x;
    const float* in; bf16_t* out; int R, C, rt, ct; long nrow0;
    if (idx < 768) {                       // wq/wk/wv: [16][1024][64] per head
        const int z = idx >> 8;
        const int hd = (idx >> 4) & 15;
        rt = idx & 15; ct = 0; R = 1024; C = 64;
        in  = (z == 0 ? wq : z == 1 ? wk : wv) + hd * 65536;
        out = WQKVT; nrow0 = z * 1024 + hd * 64;
    } else if (idx < 1024) {               // w_proj: [1024][1024]
        const int t = idx - 768; rt = t & 15; ct = t >> 4; R = 1024; C = 1024;
        in = w_proj; out = WPROJT; nrow0 = 0;
    } else if (idx < 2048) {               // w1: [1024][4096]
        const int t = idx - 1024; rt = t & 15; ct = t >> 4; R = 1024; C = 4096;
        in = w1; out = W1T; nrow0 = 0;
    } else {                               // w2: [4096][1024]
        const int t = idx - 2048; rt = t & 63; ct = t >> 6; R = 4096; C = 1024;
        in = w2; out = W2T; nrow0 = 0;
    }
    __shared__ float tile[64][65];
    const int tid = threadIdx.x;
    const int r0 = rt * 64, c0 = ct * 64;  // r = k dim, c = n dim
    const int tr = tid >> 4;
    const int tc = (tid & 15) * 4;
#pragma unroll
    for (int rr = 0; rr < 4; rr++) {
        const int r = tr + rr * 16;
        const float4 v = *(const float4*)&in[(long)(r0 + r) * C + c0 + tc];
        tile[r][tc + 0] = v.x; tile[r][tc + 1] = v.y;
        tile[r][tc + 2] = v.z; tile[r][tc + 3] = v.w;
    }
    __syncthreads();
    const int KT = R >> 5;
    const int w = tid >> 6, l = tid & 63;
    const int c = l >> 4, rr = l & 15;
#pragma unroll
    for (int it = 0; it < 2; ++it) {
        const int t8 = it * 4 + w;         // 8 fragment tiles in this 64x64 block
        const int kt = t8 >> 2;            // 0..1
        const int nb = t8 & 3;             // 0..3
        const long n = nrow0 + c0 + nb * 16 + rr;
        const int k = r0 + kt * 32 + c * 8;
        bf16x8 o;
#pragma unroll
        for (int e = 0; e < 8; e++)
            o[e] = (bf16_t)tile[kt * 32 + c * 8 + e][nb * 16 + rr];
        *(bf16x8*)&out[ftaddr((int)n, k, KT)] = o;   // lane*16B contiguous per tile
    }
}

// ---------------- layernorm: 16 rows/block, tiled-coalesced bf16 out -----
__global__ void ln_kernel(const float* __restrict__ x, const float* __restrict__ g,
                          const float* __restrict__ b, bf16_t* __restrict__ outb)
{
    __shared__ __align__(16) bf16_t ybuf[16][1032];   // +16B pad per row
    const int tid = threadIdx.x, wave = tid >> 6, lane = tid & 63;
    const int rb = blockIdx.x;                        // row-block (16 rows)
    float4 gvv[4], bvv[4];
#pragma unroll
    for (int j = 0; j < 4; j++) {
        gvv[j] = ((const float4*)g)[lane + j * 64];
        bvv[j] = ((const float4*)b)[lane + j * 64];
    }
    for (int rr = 0; rr < 4; ++rr) {
        const int lrow = wave * 4 + rr;
        const float* xr = x + (size_t)(rb * 16 + lrow) * 1024;
        float4 v[4];
        float s = 0.f, s2 = 0.f;
#pragma unroll
        for (int j = 0; j < 4; j++) {
            v[j] = ((const float4*)xr)[lane + j * 64];
            s  += v[j].x + v[j].y + v[j].z + v[j].w;
            s2 += v[j].x * v[j].x + v[j].y * v[j].y + v[j].z * v[j].z + v[j].w * v[j].w;
        }
#pragma unroll
        for (int off = 32; off >= 1; off >>= 1) {
            s  += __shfl_xor(s, off);
            s2 += __shfl_xor(s2, off);
        }
        const float mu = s * (1.0f / 1024.0f);
        const float rs = rsqrtf(fmaxf(s2 * (1.0f / 1024.0f) - mu * mu, 0.f) + 1e-5f);
#pragma unroll
        for (int j = 0; j < 4; j++) {
            bf16x4 o;
            o[0] = (bf16_t)((v[j].x - mu) * rs * gvv[j].x + bvv[j].x);
            o[1] = (bf16_t)((v[j].y - mu) * rs * gvv[j].y + bvv[j].y);
            o[2] = (bf16_t)((v[j].z - mu) * rs * gvv[j].z + bvv[j].z);
            o[3] = (bf16_t)((v[j].w - mu) * rs * gvv[j].w + bvv[j].w);
            *(bf16x4*)&ybuf[lrow][(lane + j * 64) * 4] = o;
        }
    }
    __syncthreads();
    // write phase: 32 tiles x 64 slots(16B) = 2048 slots; slot s -> s*16B
    bf16_t* outBase = outb + (size_t)rb * 32 * 512;   // KT = 32
    for (int it = 0; it < 8; ++it) {
        const int s = it * 256 + tid;
        const int kt = s >> 6, c = (s >> 4) & 3, rr = s & 15;
        const bf16x8 val = *(const bf16x8*)&ybuf[rr][kt * 32 + c * 8];
        *(bf16x8*)&outBase[(size_t)s * 8] = val;
    }
}

// ---------------- double layernorm: ln(ln(x)), tiled-coalesced out ------
__global__ void ln2x_kernel(const float* __restrict__ x, const float* __restrict__ g,
                            const float* __restrict__ b, bf16_t* __restrict__ outb)
{
    __shared__ __align__(16) bf16_t ybuf[16][1032];
    const int tid = threadIdx.x, wave = tid >> 6, lane = tid & 63;
    const int rb = blockIdx.x;
    float4 gvv[4], bvv[4];
#pragma unroll
    for (int j = 0; j < 4; j++) {
        gvv[j] = ((const float4*)g)[lane + j * 64];
        bvv[j] = ((const float4*)b)[lane + j * 64];
    }
    for (int rr = 0; rr < 4; ++rr) {
        const int lrow = wave * 4 + rr;
        const float* xr = x + (size_t)(rb * 16 + lrow) * 1024;
        float4 v[4];
        float s = 0.f, s2 = 0.f;
#pragma unroll
        for (int j = 0; j < 4; j++) {
            v[j] = ((const float4*)xr)[lane + j * 64];
            s  += v[j].x + v[j].y + v[j].z + v[j].w;
            s2 += v[j].x * v[j].x + v[j].y * v[j].y + v[j].z * v[j].z + v[j].w * v[j].w;
        }
#pragma unroll
        for (int off = 32; off >= 1; off >>= 1) {
            s  += __shfl_xor(s, off);
            s2 += __shfl_xor(s2, off);
        }
        float mu = s * (1.0f / 1024.0f);
        float rs = rsqrtf(fmaxf(s2 * (1.0f / 1024.0f) - mu * mu, 0.f) + 1e-5f);
        // first LN in registers
        s = 0.f; s2 = 0.f;
#pragma unroll
        for (int j = 0; j < 4; j++) {
            v[j].x = (v[j].x - mu) * rs * gvv[j].x + bvv[j].x;
            v[j].y = (v[j].y - mu) * rs * gvv[j].y + bvv[j].y;
            v[j].z = (v[j].z - mu) * rs * gvv[j].z + bvv[j].z;
            v[j].w = (v[j].w - mu) * rs * gvv[j].w + bvv[j].w;
            s  += v[j].x + v[j].y + v[j].z + v[j].w;
            s2 += v[j].x * v[j].x + v[j].y * v[j].y + v[j].z * v[j].z + v[j].w * v[j].w;
        }
#pragma unroll
        for (int off = 32; off >= 1; off >>= 1) {
            s  += __shfl_xor(s, off);
            s2 += __shfl_xor(s2, off);
        }
        mu = s * (1.0f / 1024.0f);
        rs = rsqrtf(fmaxf(s2 * (1.0f / 1024.0f) - mu * mu, 0.f) + 1e-5f);
#pragma unroll
        for (int j = 0; j < 4; j++) {
            bf16x4 o;
            o[0] = (bf16_t)((v[j].x - mu) * rs * gvv[j].x + bvv[j].x);
            o[1] = (bf16_t)((v[j].y - mu) * rs * gvv[j].y + bvv[j].y);
            o[2] = (bf16_t)((v[j].z - mu) * rs * gvv[j].z + bvv[j].z);
            o[3] = (bf16_t)((v[j].w - mu) * rs * gvv[j].w + bvv[j].w);
            *(bf16x4*)&ybuf[lrow][(lane + j * 64) * 4] = o;
        }
    }
    __syncthreads();
    bf16_t* outBase = outb + (size_t)rb * 32 * 512;
    for (int it = 0; it < 8; ++it) {
        const int s = it * 256 + tid;
        const int kt = s >> 6, c = (s >> 4) & 3, rr = s & 15;
        const bf16x8 val = *(const bf16x8*)&ybuf[rr][kt * 32 + c * 8];
        *(bf16x8*)&outBase[(size_t)s * 8] = val;
    }
}

// ---------------- bf16 MFMA GEMM: C = Atiled * Btiled^T (R11, unchanged) -
template<int EPI, int BNt>
__global__ __launch_bounds__(256, 2)
void gemm_bt(const bf16_t* __restrict__ A, const bf16_t* __restrict__ Bt,
             const int K,
             const float* __restrict__ bias, const float* __restrict__ resid,
             float* __restrict__ outf, bf16_t* __restrict__ outb,
             bf16_t* __restrict__ aux1, bf16_t* __restrict__ aux2,
             const int Nout)
{
    constexpr int NFRAG = BNt / 16;
    __shared__ __align__(16) bf16_t As[3][8 * 512];
    __shared__ __align__(16) bf16_t Bs[3][NFRAG * 512];
    const int tid  = threadIdx.x;
    const int wave = tid >> 6, lane = tid & 63;
    const int bm = blockIdx.x * BM, bn = blockIdx.y * BNt;
    const int KT = K >> 5;

    floatx4 acc[2][NFRAG];
#pragma unroll
    for (int i = 0; i < 2; i++)
#pragma unroll
        for (int j = 0; j < NFRAG; j++) acc[i][j] = (floatx4){0.f, 0.f, 0.f, 0.f};

    const bf16_t* gA0 = A + ((size_t)(bm / 16 + wave * 2 + 0) * KT) * 512 + lane * 8;
    const bf16_t* gA1 = A + ((size_t)(bm / 16 + wave * 2 + 1) * KT) * 512 + lane * 8;
    const int lA0 = (wave * 2 + 0) * 512;
    const int lA1 = (wave * 2 + 1) * 512;

    const bf16_t* gB0;
    const bf16_t* gB1 = nullptr;
    int lB0, lB1 = 0;
    if (BNt == 128) {
        gB0 = Bt + ((size_t)(bn / 16 + wave * 2 + 0) * KT) * 512 + lane * 8;
        gB1 = Bt + ((size_t)(bn / 16 + wave * 2 + 1) * KT) * 512 + lane * 8;
        lB0 = (wave * 2 + 0) * 512;
        lB1 = (wave * 2 + 1) * 512;
    } else {
        gB0 = Bt + ((size_t)(bn / 16 + wave) * KT) * 512 + lane * 8;
        lB0 = wave * 512;
    }

    auto stage = [&](int t, int bu) {
        const size_t off = (size_t)t * 512;
        gload16(gA0 + off, (bf16_t*)As[bu] + lA0);
        gload16(gA1 + off, (bf16_t*)As[bu] + lA1);
        gload16(gB0 + off, (bf16_t*)Bs[bu] + lB0);
        if (BNt == 128) gload16(gB1 + off, (bf16_t*)Bs[bu] + lB1);
    };

    auto compute = [&](int bu) {
        bf16x8 af[2], bfv[NFRAG];
#pragma unroll
        for (int i = 0; i < 2; i++)
            af[i] = *(const bf16x8*)&As[bu][(wave * 2 + i) * 512 + lane * 8];
#pragma unroll
        for (int j = 0; j < NFRAG; j++)
            bfv[j] = *(const bf16x8*)&Bs[bu][j * 512 + lane * 8];
#pragma unroll
        for (int i = 0; i < 2; i++)
#pragma unroll
            for (int j = 0; j < NFRAG; j++)
                acc[i][j] = __builtin_amdgcn_mfma_f32_16x16x32_bf16(af[i], bfv[j], acc[i][j], 0, 0, 0);
    };

    const int NT = K / BK;
    stage(0, 0);
    stage(1, 1);
    int bu = 0;
    for (int t = 0; t < NT - 1; ++t) {
        if (BNt == 128) asm volatile("s_waitcnt vmcnt(4)\n\ts_barrier" ::: "memory");
        else            asm volatile("s_waitcnt vmcnt(3)\n\ts_barrier" ::: "memory");
        if (t + 2 < NT) stage(t + 2, (t + 2) % 3);
        compute(bu);
        bu = (bu + 1) % 3;
    }
    asm volatile("s_waitcnt vmcnt(0)\n\ts_barrier" ::: "memory");
    compute(bu);

    const int er = (lane >> 4) * 4, ec = lane & 15;
#pragma unroll
    for (int i = 0; i < 2; i++) {
#pragma unroll
        for (int j = 0; j < NFRAG; j++) {
            const int col = bn + j * 16 + ec;
#pragma unroll
            for (int r = 0; r < 4; r++) {
                const int row = bm + wave * 32 + i * 16 + er + r;
                const float v = acc[i][j][r];
                if (EPI == 0) {
                    const int b = row >> 10, t = row & 1023;
                    if (col < 1024) {
                        const int h = col >> 6, d = col & 63;
                        outb[(size_t)((b * 16 + h) * 1024 + t) * 64 + d] = (bf16_t)v;
                    } else if (col < 2048) {
                        const int c2 = col - 1024, h = c2 >> 6, d = c2 & 63;
                        aux1[(size_t)((b * 16 + h) * 1024 + t) * 64 + d] = (bf16_t)v;
                    } else {
                        const int c2 = col - 2048, h = c2 >> 6, d = c2 & 63;
                        aux2[(size_t)((b * 16 + h) * 64 + d) * 1024 + t] = (bf16_t)v;
                    }
                } else if (EPI == 1 || EPI == 3) {
                    const size_t idx = (size_t)row * Nout + col;
                    outf[idx] = v + bias[col] + resid[idx];
                } else if (EPI == 2) {
                    outb[ftaddr(row, col, Nout >> 5)] = (bf16_t)fmaxf(v + bias[col], 0.f);
                }
            }
        }
    }
}

// ---------------- flash attention (R11, unchanged; AO written tiled) -----
__global__ __launch_bounds__(256, 4)
void attn_kernel(const bf16_t* __restrict__ Q, const bf16_t* __restrict__ Kg,
                 const bf16_t* __restrict__ Vt, bf16_t* __restrict__ Og)
{
    __shared__ __align__(16) bf16_t Ks[2][4096];
    __shared__ __align__(16) bf16_t Vs[2][4096];
    __shared__ __align__(16) bf16_t Ps[4][1024];
    const int tid = threadIdx.x, wave = tid >> 6, lane = tid & 63;
    const int bh = blockIdx.y;
    const int b = bh >> 4, h = bh & 15;
    const int q0 = blockIdx.x * 64 + wave * 16;
    const bf16_t* Qb = Q + (size_t)bh * 65536;
    const char* Kb = (const char*)(Kg + (size_t)bh * 65536);
    const char* Vb = (const char*)(Vt + (size_t)bh * 65536);
    const int fr = lane & 15, g = lane >> 4, fk = g * 8;

    const bf16x8 qf0 = *(const bf16x8*)&Qb[(size_t)(q0 + fr) * 64 + fk];
    const bf16x8 qf1 = *(const bf16x8*)&Qb[(size_t)(q0 + fr) * 64 + 32 + fk];

    floatx4 o[4];
#pragma unroll
    for (int dt = 0; dt < 4; dt++) o[dt] = (floatx4){0.f, 0.f, 0.f, 0.f};
    float lsum[4] = {0.f, 0.f, 0.f, 0.f};
    bf16_t* pw = &Ps[wave][0];
    const float sscale = 0.125f * 1.44269504088896f;

    auto stage = [&](int s0, int bu) {
#pragma unroll
        for (int t = 0; t < 2; t++) {
            const int j = wave * 2 + t;
            gload16(Kb + (size_t)(s0 + lane) * 128 + j * 16, &Ks[bu][j * 512]);
            gload16(Vb + (size_t)lane * 2048 + (size_t)s0 * 2 + j * 16, &Vs[bu][j * 512]);
        }
    };

    stage(0, 0);
    int bu = 0;
    for (int it = 0; it < 16; ++it) {
        __syncthreads();
        if (it < 15) stage((it + 1) * 64, bu ^ 1);
        const bf16_t* Kl = Ks[bu];
        const bf16_t* Vl = Vs[bu];

        floatx4 sacc[4];
#pragma unroll
        for (int ss = 0; ss < 4; ss++) sacc[ss] = (floatx4){0.f, 0.f, 0.f, 0.f};
#pragma unroll
        for (int c = 0; c < 2; c++) {
            const int ch = c * 4 + g;
            const bf16x8 qf = (c == 0) ? qf0 : qf1;
#pragma unroll
            for (int ss = 0; ss < 4; ss++) {
                const bf16x8 kf = *(const bf16x8*)&Kl[ch * 512 + (ss * 16 + fr) * 8];
                sacc[ss] = __builtin_amdgcn_mfma_f32_16x16x32_bf16(qf, kf, sacc[ss], 0, 0, 0);
            }
        }
#pragma unroll
        for (int ss = 0; ss < 4; ss++) {
#pragma unroll
            for (int r = 0; r < 4; r++) {
                const float p = __builtin_amdgcn_exp2f(sacc[ss][r] * sscale);
                lsum[r] += p;
                const int q = g * 4 + r;
                pw[(ss * 2 + (fr >> 3)) * 128 + q * 8 + (fr & 7)] = (bf16_t)p;
            }
        }
        asm volatile("s_waitcnt lgkmcnt(0)" ::: "memory");
#pragma unroll
        for (int c = 0; c < 2; c++) {
            const int ch = c * 4 + g;
            const bf16x8 pf = *(const bf16x8*)&pw[ch * 128 + fr * 8];
#pragma unroll
            for (int dt = 0; dt < 4; dt++) {
                const bf16x8 vf = *(const bf16x8*)&Vl[ch * 512 + (dt * 16 + fr) * 8];
                o[dt] = __builtin_amdgcn_mfma_f32_16x16x32_bf16(pf, vf, o[dt], 0, 0, 0);
            }
        }
        asm volatile("" ::: "memory");
        bu ^= 1;
    }
#pragma unroll
    for (int r = 0; r < 4; r++) {
        float l = lsum[r];
        l += __shfl_xor(l, 1);
        l += __shfl_xor(l, 2);
        l += __shfl_xor(l, 4);
        l += __shfl_xor(l, 8);
        lsum[r] = 1.0f / l;
    }
    const int tq = q0 + g * 4;
#pragma unroll
    for (int dt = 0; dt < 4; dt++) {
#pragma unroll
        for (int r = 0; r < 4; r++) {
            const int m = b * 1024 + tq + r;
            const int k = h * 64 + dt * 16 + fr;
            Og[ftaddr(m, k, 32)] = (bf16_t)(o[dt][r] * lsum[r]);
        }
    }
}

// -------------------------------------------------------------------------
extern "C" void kernel_launch(void* const* d_in, const int* in_sizes, int n_in,
                              void* d_out, int out_size, void* d_ws, size_t ws_size,
                              hipStream_t stream)
{
    const float* x      = (const float*)d_in[0];
    const float* wq     = (const float*)d_in[1];
    const float* wk     = (const float*)d_in[2];
    const float* wv     = (const float*)d_in[3];
    const float* w_proj = (const float*)d_in[4];
    const float* b_proj = (const float*)d_in[5];
    const float* w1     = (const float*)d_in[6];
    const float* b1     = (const float*)d_in[7];
    const float* w2     = (const float*)d_in[8];
    const float* b2     = (const float*)d_in[9];
    const float* g1     = (const float*)d_in[10];
    const float* be1    = (const float*)d_in[11];
    const float* g2     = (const float*)d_in[12];
    const float* be2    = (const float*)d_in[13];
    float* out = (float*)d_out;
    char* ws = (char*)d_ws;

    bf16_t* WQKVT = (bf16_t*)(ws + 0x0000000);  // [3072,1024] tiled, 6 MB
    bf16_t* WPROJT= (bf16_t*)(ws + 0x0600000);  // [1024,1024] tiled, 2 MB
    bf16_t* W1T   = (bf16_t*)(ws + 0x0800000);  // [4096,1024] tiled, 8 MB
    bf16_t* W2T   = (bf16_t*)(ws + 0x1000000);  // [1024,4096] tiled, 8 MB
    bf16_t* HB    = (bf16_t*)(ws + 0x1800000);  // ln1 out tiled, 8 MB
    bf16_t* Qb    = (bf16_t*)(ws + 0x2000000);  // [BH,T,64] bf16, 8 MB
    bf16_t* Kb    = (bf16_t*)(ws + 0x2800000);  // [BH,T,64] bf16, 8 MB
    bf16_t* Vtb   = (bf16_t*)(ws + 0x3000000);  // [BH,64,T] bf16, 8 MB
    bf16_t* AO    = (bf16_t*)(ws + 0x3800000);  // attn out tiled, 8 MB
    float*  X2    = (float*)(ws + 0x4000000);   // x+sa fp32 row-major, 16 MB
    bf16_t* TB    = (bf16_t*)(ws + 0x2800000);  // ln2(ln2) tiled (reuses Kb), 8 MB
    bf16_t* FF1B  = (bf16_t*)(ws + 0x5000000);  // [4096,4096] tiled, 32 MB

    dim3 blk(256);
    transpose_all<<<3072, blk, 0, stream>>>(wq, wk, wv, w_proj, w1, w2,
                                            WQKVT, WPROJT, W1T, W2T);
    ln_kernel<<<256, blk, 0, stream>>>(x, g1, be1, HB);
    gemm_bt<0, 128><<<dim3(32, 24), blk, 0, stream>>>(HB, WQKVT, 1024, nullptr, nullptr,
                                                      nullptr, Qb, Kb, Vtb, 3072);
    attn_kernel<<<dim3(16, 64), blk, 0, stream>>>(Qb, Kb, Vtb, AO);
    gemm_bt<1, 64><<<dim3(32, 16), blk, 0, stream>>>(AO, WPROJT, 1024, b_proj, x,
                                                     X2, nullptr, nullptr, nullptr, 1024);
    ln2x_kernel<<<256, blk, 0, stream>>>(X2, g2, be2, TB);
    gemm_bt<2, 128><<<dim3(32, 32), blk, 0, stream>>>(TB, W1T, 1024, b1, nullptr,
                                                      nullptr, FF1B, nullptr, nullptr, 4096);
    gemm_bt<3, 64><<<dim3(32, 16), blk, 0, stream>>>(FF1B, W2T, 4096, b2, X2,
                                                     out, nullptr, nullptr, nullptr, 1024);
}

// Round 13
// 297.542 us; speedup vs baseline: 1.0719x; 1.0649x over previous
//
#include <hip/hip_runtime.h>
#include <hip/hip_bf16.h>
#include <math.h>
#include <stdint.h>

typedef __bf16 bf16_t;
typedef __bf16 bf16x4 __attribute__((ext_vector_type(4)));
typedef __bf16 bf16x8 __attribute__((ext_vector_type(8)));
typedef float floatx4 __attribute__((ext_vector_type(4)));

#define BM 128
#define BK 32

// fragment-tiled address: 16-row x 32-k tiles, chunk-major inside
__device__ __forceinline__ size_t ftaddr(int m, int k, int KT) {
    return ((size_t)(m >> 4) * KT + (k >> 5)) * 512
         + (((k >> 3) & 3) * 16 + (m & 15)) * 8 + (k & 7);
}

__device__ __forceinline__ void gload16(const void* g, void* lds) {
    __builtin_amdgcn_global_load_lds(
        (__attribute__((address_space(1))) void*)(uintptr_t)g,
        (__attribute__((address_space(3))) void*)(uintptr_t)lds,
        16, 0, 0);
}

// ---------------- prep: weight transposes (blocks 0..3071) + ln1 (3072..3327)
__global__ void prep_kernel(const float* __restrict__ wq, const float* __restrict__ wk,
                            const float* __restrict__ wv, const float* __restrict__ w_proj,
                            const float* __restrict__ w1, const float* __restrict__ w2,
                            bf16_t* __restrict__ WQKVT, bf16_t* __restrict__ WPROJT,
                            bf16_t* __restrict__ W1T, bf16_t* __restrict__ W2T,
                            const float* __restrict__ x, const float* __restrict__ g1,
                            const float* __restrict__ be1, bf16_t* __restrict__ HB)
{
    __shared__ __align__(16) char psm[33024];
    const int tid = threadIdx.x;
    if (blockIdx.x < 3072) {
        // ---- weight transpose + cast, fragment-tiled coalesced writes ----
        float (*tile)[65] = (float(*)[65])psm;
        const int idx = blockIdx.x;
        const float* in; bf16_t* out; int R, C, rt, ct; long nrow0;
        if (idx < 768) {
            const int z = idx >> 8;
            const int hd = (idx >> 4) & 15;
            rt = idx & 15; ct = 0; R = 1024; C = 64;
            in  = (z == 0 ? wq : z == 1 ? wk : wv) + hd * 65536;
            out = WQKVT; nrow0 = z * 1024 + hd * 64;
        } else if (idx < 1024) {
            const int t = idx - 768; rt = t & 15; ct = t >> 4; R = 1024; C = 1024;
            in = w_proj; out = WPROJT; nrow0 = 0;
        } else if (idx < 2048) {
            const int t = idx - 1024; rt = t & 15; ct = t >> 4; R = 1024; C = 4096;
            in = w1; out = W1T; nrow0 = 0;
        } else {
            const int t = idx - 2048; rt = t & 63; ct = t >> 6; R = 4096; C = 1024;
            in = w2; out = W2T; nrow0 = 0;
        }
        const int r0 = rt * 64, c0 = ct * 64;
        const int tr = tid >> 4;
        const int tc = (tid & 15) * 4;
#pragma unroll
        for (int rr = 0; rr < 4; rr++) {
            const int r = tr + rr * 16;
            const float4 v = *(const float4*)&in[(long)(r0 + r) * C + c0 + tc];
            tile[r][tc + 0] = v.x; tile[r][tc + 1] = v.y;
            tile[r][tc + 2] = v.z; tile[r][tc + 3] = v.w;
        }
        __syncthreads();
        const int KT = R >> 5;
        const int w = tid >> 6, l = tid & 63;
        const int c = l >> 4, rr2 = l & 15;
#pragma unroll
        for (int it = 0; it < 2; ++it) {
            const int t8 = it * 4 + w;
            const int kt = t8 >> 2;
            const int nb = t8 & 3;
            const long n = nrow0 + c0 + nb * 16 + rr2;
            const int k = r0 + kt * 32 + c * 8;
            bf16x8 o;
#pragma unroll
            for (int e = 0; e < 8; e++)
                o[e] = (bf16_t)tile[kt * 32 + c * 8 + e][nb * 16 + rr2];
            *(bf16x8*)&out[ftaddr((int)n, k, KT)] = o;
        }
    } else {
        // ---- layernorm, 16 rows/block, tiled-coalesced bf16 out ----
        bf16_t (*ybuf)[1032] = (bf16_t(*)[1032])psm;
        const int wave = tid >> 6, lane = tid & 63;
        const int rb = blockIdx.x - 3072;
        float4 gvv[4], bvv[4];
#pragma unroll
        for (int j = 0; j < 4; j++) {
            gvv[j] = ((const float4*)g1)[lane + j * 64];
            bvv[j] = ((const float4*)be1)[lane + j * 64];
        }
#pragma unroll
        for (int rr = 0; rr < 4; ++rr) {
            const int lrow = wave * 4 + rr;
            const float* xr = x + (size_t)(rb * 16 + lrow) * 1024;
            float4 v[4];
            float s = 0.f, s2 = 0.f;
#pragma unroll
            for (int j = 0; j < 4; j++) {
                v[j] = ((const float4*)xr)[lane + j * 64];
                s  += v[j].x + v[j].y + v[j].z + v[j].w;
                s2 += v[j].x * v[j].x + v[j].y * v[j].y + v[j].z * v[j].z + v[j].w * v[j].w;
            }
#pragma unroll
            for (int off = 32; off >= 1; off >>= 1) {
                s  += __shfl_xor(s, off);
                s2 += __shfl_xor(s2, off);
            }
            const float mu = s * (1.0f / 1024.0f);
            const float rs = rsqrtf(fmaxf(s2 * (1.0f / 1024.0f) - mu * mu, 0.f) + 1e-5f);
#pragma unroll
            for (int j = 0; j < 4; j++) {
                bf16x4 o;
                o[0] = (bf16_t)((v[j].x - mu) * rs * gvv[j].x + bvv[j].x);
                o[1] = (bf16_t)((v[j].y - mu) * rs * gvv[j].y + bvv[j].y);
                o[2] = (bf16_t)((v[j].z - mu) * rs * gvv[j].z + bvv[j].z);
                o[3] = (bf16_t)((v[j].w - mu) * rs * gvv[j].w + bvv[j].w);
                *(bf16x4*)&ybuf[lrow][(lane + j * 64) * 4] = o;
            }
        }
        __syncthreads();
        bf16_t* outBase = HB + (size_t)rb * 32 * 512;
#pragma unroll
        for (int it = 0; it < 8; ++it) {
            const int s = it * 256 + tid;
            const int kt = s >> 6, c = (s >> 4) & 3, rr2 = s & 15;
            const bf16x8 val = *(const bf16x8*)&ybuf[rr2][kt * 32 + c * 8];
            *(bf16x8*)&outBase[(size_t)s * 8] = val;
        }
    }
}

// ---------------- double layernorm: ln(ln(x)), tiled-coalesced out ------
__global__ void ln2x_kernel(const float* __restrict__ x, const float* __restrict__ g,
                            const float* __restrict__ b, bf16_t* __restrict__ outb)
{
    __shared__ __align__(16) bf16_t ybuf[16][1032];
    const int tid = threadIdx.x, wave = tid >> 6, lane = tid & 63;
    const int rb = blockIdx.x;
    float4 gvv[4], bvv[4];
#pragma unroll
    for (int j = 0; j < 4; j++) {
        gvv[j] = ((const float4*)g)[lane + j * 64];
        bvv[j] = ((const float4*)b)[lane + j * 64];
    }
#pragma unroll
    for (int rr = 0; rr < 4; ++rr) {
        const int lrow = wave * 4 + rr;
        const float* xr = x + (size_t)(rb * 16 + lrow) * 1024;
        float4 v[4];
        float s = 0.f, s2 = 0.f;
#pragma unroll
        for (int j = 0; j < 4; j++) {
            v[j] = ((const float4*)xr)[lane + j * 64];
            s  += v[j].x + v[j].y + v[j].z + v[j].w;
            s2 += v[j].x * v[j].x + v[j].y * v[j].y + v[j].z * v[j].z + v[j].w * v[j].w;
        }
#pragma unroll
        for (int off = 32; off >= 1; off >>= 1) {
            s  += __shfl_xor(s, off);
            s2 += __shfl_xor(s2, off);
        }
        float mu = s * (1.0f / 1024.0f);
        float rs = rsqrtf(fmaxf(s2 * (1.0f / 1024.0f) - mu * mu, 0.f) + 1e-5f);
        s = 0.f; s2 = 0.f;
#pragma unroll
        for (int j = 0; j < 4; j++) {
            v[j].x = (v[j].x - mu) * rs * gvv[j].x + bvv[j].x;
            v[j].y = (v[j].y - mu) * rs * gvv[j].y + bvv[j].y;
            v[j].z = (v[j].z - mu) * rs * gvv[j].z + bvv[j].z;
            v[j].w = (v[j].w - mu) * rs * gvv[j].w + bvv[j].w;
            s  += v[j].x + v[j].y + v[j].z + v[j].w;
            s2 += v[j].x * v[j].x + v[j].y * v[j].y + v[j].z * v[j].z + v[j].w * v[j].w;
        }
#pragma unroll
        for (int off = 32; off >= 1; off >>= 1) {
            s  += __shfl_xor(s, off);
            s2 += __shfl_xor(s2, off);
        }
        mu = s * (1.0f / 1024.0f);
        rs = rsqrtf(fmaxf(s2 * (1.0f / 1024.0f) - mu * mu, 0.f) + 1e-5f);
#pragma unroll
        for (int j = 0; j < 4; j++) {
            bf16x4 o;
            o[0] = (bf16_t)((v[j].x - mu) * rs * gvv[j].x + bvv[j].x);
            o[1] = (bf16_t)((v[j].y - mu) * rs * gvv[j].y + bvv[j].y);
            o[2] = (bf16_t)((v[j].z - mu) * rs * gvv[j].z + bvv[j].z);
            o[3] = (bf16_t)((v[j].w - mu) * rs * gvv[j].w + bvv[j].w);
            *(bf16x4*)&ybuf[lrow][(lane + j * 64) * 4] = o;
        }
    }
    __syncthreads();
    bf16_t* outBase = outb + (size_t)rb * 32 * 512;
#pragma unroll
    for (int it = 0; it < 8; ++it) {
        const int s = it * 256 + tid;
        const int kt = s >> 6, c = (s >> 4) & 3, rr2 = s & 15;
        const bf16x8 val = *(const bf16x8*)&ybuf[rr2][kt * 32 + c * 8];
        *(bf16x8*)&outBase[(size_t)s * 8] = val;
    }
}

// ---------------- bf16 MFMA GEMM: C = Atiled * Btiled^T ------------------
// R11 pipeline, conflicts=0. QKV V-blocks (EPI=0, bn>=2048): epilogue stages
// through the dead As/Bs LDS (128x128 transpose, pad 136 -> 2-way/free) and
// writes Vtb fully coalesced (16B/lane contiguous t) — was 2B @ 2KB stride.
template<int EPI, int BNt>
__global__ __launch_bounds__(256, 2)
void gemm_bt(const bf16_t* __restrict__ A, const bf16_t* __restrict__ Bt,
             const int K,
             const float* __restrict__ bias, const float* __restrict__ resid,
             float* __restrict__ outf, bf16_t* __restrict__ outb,
             bf16_t* __restrict__ aux1, bf16_t* __restrict__ aux2,
             const int Nout)
{
    constexpr int NFRAG = BNt / 16;
    constexpr int ASZ = 3 * 8 * 512;
    constexpr int BSZ = 3 * NFRAG * 512;
    __shared__ __align__(16) bf16_t smem[ASZ + BSZ];
    bf16_t* Asb = smem;
    bf16_t* Bsb = smem + ASZ;
    const int tid  = threadIdx.x;
    const int wave = tid >> 6, lane = tid & 63;
    const int bm = blockIdx.x * BM, bn = blockIdx.y * BNt;
    const int KT = K >> 5;

    floatx4 acc[2][NFRAG];
#pragma unroll
    for (int i = 0; i < 2; i++)
#pragma unroll
        for (int j = 0; j < NFRAG; j++) acc[i][j] = (floatx4){0.f, 0.f, 0.f, 0.f};

    const bf16_t* gA0 = A + ((size_t)(bm / 16 + wave * 2 + 0) * KT) * 512 + lane * 8;
    const bf16_t* gA1 = A + ((size_t)(bm / 16 + wave * 2 + 1) * KT) * 512 + lane * 8;
    const int lA0 = (wave * 2 + 0) * 512;
    const int lA1 = (wave * 2 + 1) * 512;

    const bf16_t* gB0;
    const bf16_t* gB1 = nullptr;
    int lB0, lB1 = 0;
    if (BNt == 128) {
        gB0 = Bt + ((size_t)(bn / 16 + wave * 2 + 0) * KT) * 512 + lane * 8;
        gB1 = Bt + ((size_t)(bn / 16 + wave * 2 + 1) * KT) * 512 + lane * 8;
        lB0 = (wave * 2 + 0) * 512;
        lB1 = (wave * 2 + 1) * 512;
    } else {
        gB0 = Bt + ((size_t)(bn / 16 + wave) * KT) * 512 + lane * 8;
        lB0 = wave * 512;
    }

    auto stage = [&](int t, int bu) {
        const size_t off = (size_t)t * 512;
        gload16(gA0 + off, Asb + bu * 4096 + lA0);
        gload16(gA1 + off, Asb + bu * 4096 + lA1);
        gload16(gB0 + off, Bsb + bu * (NFRAG * 512) + lB0);
        if (BNt == 128) gload16(gB1 + off, Bsb + bu * (NFRAG * 512) + lB1);
    };

    auto compute = [&](int bu) {
        bf16x8 af[2], bfv[NFRAG];
#pragma unroll
        for (int i = 0; i < 2; i++)
            af[i] = *(const bf16x8*)&Asb[bu * 4096 + (wave * 2 + i) * 512 + lane * 8];
#pragma unroll
        for (int j = 0; j < NFRAG; j++)
            bfv[j] = *(const bf16x8*)&Bsb[bu * (NFRAG * 512) + j * 512 + lane * 8];
#pragma unroll
        for (int i = 0; i < 2; i++)
#pragma unroll
            for (int j = 0; j < NFRAG; j++)
                acc[i][j] = __builtin_amdgcn_mfma_f32_16x16x32_bf16(af[i], bfv[j], acc[i][j], 0, 0, 0);
    };

    const int NT = K / BK;
    stage(0, 0);
    stage(1, 1);
    int bu = 0;
    for (int t = 0; t < NT - 1; ++t) {
        if (BNt == 128) asm volatile("s_waitcnt vmcnt(4)\n\ts_barrier" ::: "memory");
        else            asm volatile("s_waitcnt vmcnt(3)\n\ts_barrier" ::: "memory");
        if (t + 2 < NT) stage(t + 2, (t + 2) % 3);
        compute(bu);
        bu = (bu + 1) % 3;
    }
    asm volatile("s_waitcnt vmcnt(0)\n\ts_barrier" ::: "memory");
    compute(bu);

    const int er = (lane >> 4) * 4, ec = lane & 15;
    if (EPI == 0 && bn >= 2048) {
        // V-block: LDS transpose then coalesced [d][t] writes
        __syncthreads();                      // staging LDS now dead
        bf16_t* scr = smem;                   // 128 x 136 (pad) bf16 = 34 KB
#pragma unroll
        for (int i = 0; i < 2; i++)
#pragma unroll
            for (int j = 0; j < NFRAG; j++)
#pragma unroll
                for (int r = 0; r < 4; r++)
                    scr[(j * 16 + ec) * 136 + wave * 32 + i * 16 + er + r] =
                        (bf16_t)acc[i][j][r];
        __syncthreads();
        const int bq = bm >> 10, tmod = bm & 1023, h0 = (bn - 2048) >> 6;
#pragma unroll
        for (int it = 0; it < 8; ++it) {
            const int c = it * 256 + tid;
            const int dl = c >> 4, t16 = c & 15;
            const bf16x8 val = *(const bf16x8*)&scr[dl * 136 + t16 * 8];
            const int h = h0 + (dl >> 6), dd = dl & 63;
            *(bf16x8*)&aux2[(size_t)((bq * 16 + h) * 64 + dd) * 1024 + tmod + t16 * 8] = val;
        }
        return;
    }
#pragma unroll
    for (int i = 0; i < 2; i++) {
#pragma unroll
        for (int j = 0; j < NFRAG; j++) {
            const int col = bn + j * 16 + ec;
#pragma unroll
            for (int r = 0; r < 4; r++) {
                const int row = bm + wave * 32 + i * 16 + er + r;
                const float v = acc[i][j][r];
                if (EPI == 0) {
                    const int b = row >> 10, t = row & 1023;
                    if (col < 1024) {
                        const int h = col >> 6, d = col & 63;
                        outb[(size_t)((b * 16 + h) * 1024 + t) * 64 + d] = (bf16_t)v;
                    } else {
                        const int c2 = col - 1024, h = c2 >> 6, d = c2 & 63;
                        aux1[(size_t)((b * 16 + h) * 1024 + t) * 64 + d] = (bf16_t)v;
                    }
                } else if (EPI == 1 || EPI == 3) {
                    const size_t idx = (size_t)row * Nout + col;
                    outf[idx] = v + bias[col] + resid[idx];
                } else if (EPI == 2) {
                    outb[ftaddr(row, col, Nout >> 5)] = (bf16_t)fmaxf(v + bias[col], 0.f);
                }
            }
        }
    }
}

// ---------------- flash attention (unchanged; AO written tiled) ----------
__global__ __launch_bounds__(256, 4)
void attn_kernel(const bf16_t* __restrict__ Q, const bf16_t* __restrict__ Kg,
                 const bf16_t* __restrict__ Vt, bf16_t* __restrict__ Og)
{
    __shared__ __align__(16) bf16_t Ks[2][4096];
    __shared__ __align__(16) bf16_t Vs[2][4096];
    __shared__ __align__(16) bf16_t Ps[4][1024];
    const int tid = threadIdx.x, wave = tid >> 6, lane = tid & 63;
    const int bh = blockIdx.y;
    const int b = bh >> 4, h = bh & 15;
    const int q0 = blockIdx.x * 64 + wave * 16;
    const bf16_t* Qb = Q + (size_t)bh * 65536;
    const char* Kb = (const char*)(Kg + (size_t)bh * 65536);
    const char* Vb = (const char*)(Vt + (size_t)bh * 65536);
    const int fr = lane & 15, g = lane >> 4, fk = g * 8;

    const bf16x8 qf0 = *(const bf16x8*)&Qb[(size_t)(q0 + fr) * 64 + fk];
    const bf16x8 qf1 = *(const bf16x8*)&Qb[(size_t)(q0 + fr) * 64 + 32 + fk];

    floatx4 o[4];
#pragma unroll
    for (int dt = 0; dt < 4; dt++) o[dt] = (floatx4){0.f, 0.f, 0.f, 0.f};
    float lsum[4] = {0.f, 0.f, 0.f, 0.f};
    bf16_t* pw = &Ps[wave][0];
    const float sscale = 0.125f * 1.44269504088896f;

    auto stage = [&](int s0, int bu) {
#pragma unroll
        for (int t = 0; t < 2; t++) {
            const int j = wave * 2 + t;
            gload16(Kb + (size_t)(s0 + lane) * 128 + j * 16, &Ks[bu][j * 512]);
            gload16(Vb + (size_t)lane * 2048 + (size_t)s0 * 2 + j * 16, &Vs[bu][j * 512]);
        }
    };

    stage(0, 0);
    int bu = 0;
    for (int it = 0; it < 16; ++it) {
        __syncthreads();
        if (it < 15) stage((it + 1) * 64, bu ^ 1);
        const bf16_t* Kl = Ks[bu];
        const bf16_t* Vl = Vs[bu];

        floatx4 sacc[4];
#pragma unroll
        for (int ss = 0; ss < 4; ss++) sacc[ss] = (floatx4){0.f, 0.f, 0.f, 0.f};
#pragma unroll
        for (int c = 0; c < 2; c++) {
            const int ch = c * 4 + g;
            const bf16x8 qf = (c == 0) ? qf0 : qf1;
#pragma unroll
            for (int ss = 0; ss < 4; ss++) {
                const bf16x8 kf = *(const bf16x8*)&Kl[ch * 512 + (ss * 16 + fr) * 8];
                sacc[ss] = __builtin_amdgcn_mfma_f32_16x16x32_bf16(qf, kf, sacc[ss], 0, 0, 0);
            }
        }
#pragma unroll
        for (int ss = 0; ss < 4; ss++) {
#pragma unroll
            for (int r = 0; r < 4; r++) {
                const float p = __builtin_amdgcn_exp2f(sacc[ss][r] * sscale);
                lsum[r] += p;
                const int q = g * 4 + r;
                pw[(ss * 2 + (fr >> 3)) * 128 + q * 8 + (fr & 7)] = (bf16_t)p;
            }
        }
        asm volatile("s_waitcnt lgkmcnt(0)" ::: "memory");
#pragma unroll
        for (int c = 0; c < 2; c++) {
            const int ch = c * 4 + g;
            const bf16x8 pf = *(const bf16x8*)&pw[ch * 128 + fr * 8];
#pragma unroll
            for (int dt = 0; dt < 4; dt++) {
                const bf16x8 vf = *(const bf16x8*)&Vl[ch * 512 + (dt * 16 + fr) * 8];
                o[dt] = __builtin_amdgcn_mfma_f32_16x16x32_bf16(pf, vf, o[dt], 0, 0, 0);
            }
        }
        asm volatile("" ::: "memory");
        bu ^= 1;
    }
#pragma unroll
    for (int r = 0; r < 4; r++) {
        float l = lsum[r];
        l += __shfl_xor(l, 1);
        l += __shfl_xor(l, 2);
        l += __shfl_xor(l, 4);
        l += __shfl_xor(l, 8);
        lsum[r] = 1.0f / l;
    }
    const int tq = q0 + g * 4;
#pragma unroll
    for (int dt = 0; dt < 4; dt++) {
#pragma unroll
        for (int r = 0; r < 4; r++) {
            const int m = b * 1024 + tq + r;
            const int k = h * 64 + dt * 16 + fr;
            Og[ftaddr(m, k, 32)] = (bf16_t)(o[dt][r] * lsum[r]);
        }
    }
}

// -------------------------------------------------------------------------
extern "C" void kernel_launch(void* const* d_in, const int* in_sizes, int n_in,
                              void* d_out, int out_size, void* d_ws, size_t ws_size,
                              hipStream_t stream)
{
    const float* x      = (const float*)d_in[0];
    const float* wq     = (const float*)d_in[1];
    const float* wk     = (const float*)d_in[2];
    const float* wv     = (const float*)d_in[3];
    const float* w_proj = (const float*)d_in[4];
    const float* b_proj = (const float*)d_in[5];
    const float* w1     = (const float*)d_in[6];
    const float* b1     = (const float*)d_in[7];
    const float* w2     = (const float*)d_in[8];
    const float* b2     = (const float*)d_in[9];
    const float* g1     = (const float*)d_in[10];
    const float* be1    = (const float*)d_in[11];
    const float* g2     = (const float*)d_in[12];
    const float* be2    = (const float*)d_in[13];
    float* out = (float*)d_out;
    char* ws = (char*)d_ws;

    bf16_t* WQKVT = (bf16_t*)(ws + 0x0000000);  // [3072,1024] tiled, 6 MB
    bf16_t* WPROJT= (bf16_t*)(ws + 0x0600000);  // [1024,1024] tiled, 2 MB
    bf16_t* W1T   = (bf16_t*)(ws + 0x0800000);  // [4096,1024] tiled, 8 MB
    bf16_t* W2T   = (bf16_t*)(ws + 0x1000000);  // [1024,4096] tiled, 8 MB
    bf16_t* HB    = (bf16_t*)(ws + 0x1800000);  // ln1 out tiled, 8 MB
    bf16_t* Qb    = (bf16_t*)(ws + 0x2000000);  // [BH,T,64] bf16, 8 MB
    bf16_t* Kb    = (bf16_t*)(ws + 0x2800000);  // [BH,T,64] bf16, 8 MB
    bf16_t* Vtb   = (bf16_t*)(ws + 0x3000000);  // [BH,64,T] bf16, 8 MB
    bf16_t* AO    = (bf16_t*)(ws + 0x3800000);  // attn out tiled, 8 MB
    float*  X2    = (float*)(ws + 0x4000000);   // x+sa fp32 row-major, 16 MB
    bf16_t* TB    = (bf16_t*)(ws + 0x2800000);  // ln2(ln2) tiled (reuses Kb), 8 MB
    bf16_t* FF1B  = (bf16_t*)(ws + 0x5000000);  // [4096,4096] tiled, 32 MB

    dim3 blk(256);
    prep_kernel<<<3328, blk, 0, stream>>>(wq, wk, wv, w_proj, w1, w2,
                                          WQKVT, WPROJT, W1T, W2T,
                                          x, g1, be1, HB);
    gemm_bt<0, 128><<<dim3(32, 24), blk, 0, stream>>>(HB, WQKVT, 1024, nullptr, nullptr,
                                                      nullptr, Qb, Kb, Vtb, 3072);
    attn_kernel<<<dim3(16, 64), blk, 0, stream>>>(Qb, Kb, Vtb, AO);
    gemm_bt<1, 64><<<dim3(32, 16), blk, 0, stream>>>(AO, WPROJT, 1024, b_proj, x,
                                                     X2, nullptr, nullptr, nullptr, 1024);
    ln2x_kernel<<<256, blk, 0, stream>>>(X2, g2, be2, TB);
    gemm_bt<2, 128><<<dim3(32, 32), blk, 0, stream>>>(TB, W1T, 1024, b1, nullptr,
                                                      nullptr, FF1B, nullptr, nullptr, 4096);
    gemm_bt<3, 64><<<dim3(32, 16), blk, 0, stream>>>(FF1B, W2T, 4096, b2, X2,
                                                     out, nullptr, nullptr, nullptr, 1024);
}